// Round 1
// baseline (1193.310 us; speedup 1.0000x reference)
//
#include <hip/hip_runtime.h>
#include <cstddef>
#include <cstdint>

#define NF 512
#define SND 256
#define NG 256
#define EPSV 1e-5f

typedef __attribute__((ext_vector_type(8))) short bf16x8;
typedef __attribute__((ext_vector_type(4))) float f32x4;

__device__ __forceinline__ float bf2f(unsigned short u) {
  return __uint_as_float(((unsigned int)u) << 16);
}
__device__ __forceinline__ unsigned short f2bf(float f) {
  unsigned int u = __float_as_uint(f);
  return (unsigned short)((u + 0x7fffu + ((u >> 16) & 1u)) >> 16);
}
__device__ __forceinline__ unsigned int pack2bf(float a, float b) {
  return (unsigned int)f2bf(a) | ((unsigned int)f2bf(b) << 16);
}
__device__ __forceinline__ float loadf(float v) { return v; }
__device__ __forceinline__ float loadf(unsigned short v) { return bf2f(v); }

// ---------------- small kernels ----------------
__global__ void offsets_kernel(const int* __restrict__ batch, int* __restrict__ offs, int M) {
  int t = threadIdx.x + blockIdx.x * blockDim.x;
  if (t > NG) return;
  if (t == NG) { offs[NG] = M; return; }
  int lo = 0, hi = M;
  while (lo < hi) { int mid = (lo + hi) >> 1; if (batch[mid] < t) lo = mid + 1; else hi = mid; }
  offs[t] = lo;
}

__global__ void wconv_kernel(const float* __restrict__ w1, const float* __restrict__ w2,
                             const float* __restrict__ w3, const float* __restrict__ w4,
                             const float* __restrict__ w5,
                             unsigned short* __restrict__ o1, unsigned short* __restrict__ o2,
                             unsigned short* __restrict__ o3, unsigned short* __restrict__ o4,
                             unsigned short* __restrict__ o5) {
  int i = threadIdx.x + blockIdx.x * 256;
  if (i < 131072) { o1[i] = f2bf(w1[i]); o5[i] = f2bf(w5[i]); }
  if (i < 65536)  { o2[i] = f2bf(w2[i]); o3[i] = f2bf(w3[i]); o4[i] = f2bf(w4[i]); }
}

template <typename T, int F>
__global__ void stats_seg(const T* __restrict__ X, const int* __restrict__ offs,
                          float* __restrict__ sum, float* __restrict__ sumsq) {
  const int g = blockIdx.x;
  const int s = offs[g], e = offs[g + 1];
  constexpr int NJ = F / 256;
  float a0[NJ], a1[NJ];
#pragma unroll
  for (int j = 0; j < NJ; ++j) { a0[j] = 0.f; a1[j] = 0.f; }
  for (int r = s + (int)blockIdx.y; r < e; r += (int)gridDim.y) {
    const T* row = X + (size_t)r * F;
#pragma unroll
    for (int j = 0; j < NJ; ++j) {
      float v = loadf(row[threadIdx.x + j * 256]);
      a0[j] += v; a1[j] += v * v;
    }
  }
#pragma unroll
  for (int j = 0; j < NJ; ++j) {
    int f = threadIdx.x + j * 256;
    atomicAdd(&sum[g * F + f], a0[j]);
    atomicAdd(&sumsq[g * F + f], a1[j]);
  }
}

template <typename T>
__global__ void stats_global(const T* __restrict__ X, int M,
                             float* __restrict__ sum, float* __restrict__ sumsq) {
  const int f = threadIdx.x;  // F == 256
  float a0 = 0.f, a1 = 0.f;
  for (int r = blockIdx.x; r < M; r += gridDim.x) {
    float v = loadf(X[(size_t)r * SND + f]);
    a0 += v; a1 += v * v;
  }
  atomicAdd(&sum[f], a0);
  atomicAdd(&sumsq[f], a1);
}

__global__ void finalize_kernel(const float* __restrict__ sum, const float* __restrict__ sumsq,
                                const float* __restrict__ w, const float* __restrict__ b,
                                const float* __restrict__ ms, const int* __restrict__ offs,
                                int fixed_cnt, int F,
                                float* __restrict__ sc, float* __restrict__ sh) {
  int idx = threadIdx.x + blockIdx.x * 256;
  int g = idx / F, f = idx - g * F;
  float cnt = offs ? (float)(offs[g + 1] - offs[g]) : (float)fixed_cnt;
  cnt = fmaxf(cnt, 1.0f);
  float mean = sum[idx] / cnt;
  float ex2  = sumsq[idx] / cnt;
  float mm = mean * ms[f];
  float var = ex2 - 2.f * mm * mean + mm * mm;  // E[(x-mean*ms)^2]
  float rstd = rsqrtf(var + EPSV);
  float s = w[f] * rstd;
  sc[idx] = s;
  sh[idx] = b[f] - mm * s;
}

// ---------------- fused norm(+prelu) -> bf16 MFMA GEMM -> (+resid) ----------------
// out[m][n] = sum_k act(norm(X[m][k])) * W[n][k] + lb[n]   (optionally +res, *0.5)
template <int K, bool IN_BF, bool PRELU, bool RESID, bool OUT_BF>
__global__ __launch_bounds__(256, 2)
void gemm_norm(const void* __restrict__ Xv, const unsigned short* __restrict__ Wb,
               const float* __restrict__ lb_, const float* __restrict__ SC,
               const float* __restrict__ SH, const int* __restrict__ batch,
               const float* __restrict__ pa, const unsigned short* __restrict__ resid,
               void* __restrict__ outv, int M, int N) {
  constexpr int BK = 64;
  constexpr int LDA = BK + 8;  // 144B row stride: 16B aligned, 2-way bank alias (free)
  __shared__ __align__(16) unsigned short sA[128 * LDA];
  __shared__ __align__(16) unsigned short sB[128 * LDA];
  __shared__ int sG[128];

  const int tid = threadIdx.x;
  const int m0 = blockIdx.y * 128;
  const int n0 = blockIdx.x * 128;
  const int wave = tid >> 6;
  const int lane = tid & 63;
  const int wm = wave & 1, wn = wave >> 1;  // 2x2 waves -> 64x64 each
  const int qd = lane >> 4;
  const int l15 = lane & 15;
  const int rl0 = tid >> 4;
  const int cq = tid & 15;

  float aval = 0.f;
  if (PRELU) aval = pa[0];

  if (tid < 128) {
    int r = m0 + tid;
    sG[tid] = (batch != nullptr && r < M) ? batch[r] : 0;
  }
  __syncthreads();

  int gReg[8];
#pragma unroll
  for (int it = 0; it < 8; ++it) gReg[it] = sG[rl0 + it * 16];

  f32x4 acc[4][4];
#pragma unroll
  for (int mi = 0; mi < 4; ++mi)
#pragma unroll
    for (int ni = 0; ni < 4; ++ni) acc[mi][ni] = (f32x4){0.f, 0.f, 0.f, 0.f};

  const float* Xf = (const float*)Xv;
  const unsigned short* Xh = (const unsigned short*)Xv;

  for (int kt = 0; kt < K / BK; ++kt) {
    const int kk = kt * BK + cq * 4;
    // ---- stage A: load, normalize (1 fma), prelu, pack bf16 ----
#pragma unroll
    for (int it = 0; it < 8; ++it) {
      const int rl = rl0 + it * 16;
      const int row = m0 + rl;
      float vx = 0.f, vy = 0.f, vz = 0.f, vw = 0.f;
      if (row < M) {
        if (IN_BF) {
          const uint2 u = *(const uint2*)(Xh + (size_t)row * K + kk);
          vx = __uint_as_float(u.x << 16);
          vy = __uint_as_float(u.x & 0xffff0000u);
          vz = __uint_as_float(u.y << 16);
          vw = __uint_as_float(u.y & 0xffff0000u);
        } else {
          const float4 u = *(const float4*)(Xf + (size_t)row * K + kk);
          vx = u.x; vy = u.y; vz = u.z; vw = u.w;
        }
      }
      const int g = gReg[it];
      const float4 s4 = *(const float4*)(SC + (size_t)g * K + kk);
      const float4 h4 = *(const float4*)(SH + (size_t)g * K + kk);
      vx = fmaf(vx, s4.x, h4.x);
      vy = fmaf(vy, s4.y, h4.y);
      vz = fmaf(vz, s4.z, h4.z);
      vw = fmaf(vw, s4.w, h4.w);
      if (PRELU) {
        vx = vx >= 0.f ? vx : aval * vx;
        vy = vy >= 0.f ? vy : aval * vy;
        vz = vz >= 0.f ? vz : aval * vz;
        vw = vw >= 0.f ? vw : aval * vw;
      }
      *(uint2*)(&sA[rl * LDA + cq * 4]) = make_uint2(pack2bf(vx, vy), pack2bf(vz, vw));
    }
    // ---- stage B (bf16 weights, N x K row-major) ----
#pragma unroll
    for (int it = 0; it < 8; ++it) {
      const int rl = rl0 + it * 16;
      const uint2 wv = *(const uint2*)(Wb + (size_t)(n0 + rl) * K + kk);
      *(uint2*)(&sB[rl * LDA + cq * 4]) = wv;
    }
    __syncthreads();
    // ---- MFMA: A[m=l15][k=qd*8+j], B[n=l15][k=qd*8+j] ----
#pragma unroll
    for (int ks = 0; ks < 2; ++ks) {
      bf16x8 af[4], bfr[4];
#pragma unroll
      for (int mi = 0; mi < 4; ++mi)
        af[mi] = *(const bf16x8*)(&sA[(wm * 64 + mi * 16 + l15) * LDA + ks * 32 + qd * 8]);
#pragma unroll
      for (int ni = 0; ni < 4; ++ni)
        bfr[ni] = *(const bf16x8*)(&sB[(wn * 64 + ni * 16 + l15) * LDA + ks * 32 + qd * 8]);
#pragma unroll
      for (int mi = 0; mi < 4; ++mi)
#pragma unroll
        for (int ni = 0; ni < 4; ++ni)
          acc[mi][ni] = __builtin_amdgcn_mfma_f32_16x16x32_bf16(af[mi], bfr[ni], acc[mi][ni], 0, 0, 0);
    }
    __syncthreads();
  }

  // ---- epilogue: C/D row=qd*4+i, col=l15 ----
  float lb[4];
#pragma unroll
  for (int ni = 0; ni < 4; ++ni) lb[ni] = lb_[n0 + wn * 64 + ni * 16 + l15];
  float* outF = (float*)outv;
  unsigned short* outH = (unsigned short*)outv;
#pragma unroll
  for (int mi = 0; mi < 4; ++mi) {
#pragma unroll
    for (int i = 0; i < 4; ++i) {
      const int row = m0 + wm * 64 + mi * 16 + qd * 4 + i;
      if (row >= M) continue;
#pragma unroll
      for (int ni = 0; ni < 4; ++ni) {
        const int col = n0 + wn * 64 + ni * 16 + l15;
        float v = acc[mi][ni][i] + lb[ni];
        if (RESID) v = 0.5f * (v + bf2f(resid[(size_t)row * N + col]));
        if (OUT_BF) outH[(size_t)row * N + col] = f2bf(v);
        else        outF[(size_t)row * N + col] = v;
      }
    }
  }
}

// ---------------- launch ----------------
extern "C" void kernel_launch(void* const* d_in, const int* in_sizes, int n_in,
                              void* d_out, int out_size, void* d_ws, size_t ws_size,
                              hipStream_t stream) {
  const float* x    = (const float*)d_in[0];
  const int* batch  = (const int*)d_in[1];
  const float* gw1 = (const float*)d_in[2],  *gb1 = (const float*)d_in[3],  *gm1 = (const float*)d_in[4];
  const float* gw2 = (const float*)d_in[5],  *gb2 = (const float*)d_in[6],  *gm2 = (const float*)d_in[7];
  const float* gw3 = (const float*)d_in[8],  *gb3 = (const float*)d_in[9],  *gm3 = (const float*)d_in[10];
  const float* gw4 = (const float*)d_in[11], *gb4 = (const float*)d_in[12], *gm4 = (const float*)d_in[13];
  const float* gw5 = (const float*)d_in[14], *gb5 = (const float*)d_in[15], *gm5 = (const float*)d_in[16];
  const float* W1 = (const float*)d_in[17], *b1 = (const float*)d_in[18];
  const float* W2 = (const float*)d_in[19], *b2 = (const float*)d_in[20];
  const float* W3 = (const float*)d_in[21], *b3 = (const float*)d_in[22];
  const float* W4 = (const float*)d_in[23], *b4 = (const float*)d_in[24];
  const float* W5 = (const float*)d_in[25], *b5 = (const float*)d_in[26];
  const float* a2 = (const float*)d_in[27], *a3 = (const float*)d_in[28];
  const float* a4 = (const float*)d_in[29], *a5 = (const float*)d_in[30];
  float* out = (float*)d_out;
  (void)n_in; (void)out_size; (void)ws_size;

  const int M = in_sizes[0] / NF;
  const int MT = (M + 127) / 128;

  char* wsp = (char*)d_ws;
  size_t off = 0;
  auto take = [&](size_t bytes) -> void* {
    void* p = wsp + off;
    off = (off + bytes + 255) & ~(size_t)255;
    return p;
  };
  int* offs            = (int*)take((NG + 1) * sizeof(int));
  unsigned short* Wb1  = (unsigned short*)take((size_t)SND * NF * 2);
  unsigned short* Wb2  = (unsigned short*)take((size_t)SND * SND * 2);
  unsigned short* Wb3  = (unsigned short*)take((size_t)SND * SND * 2);
  unsigned short* Wb4  = (unsigned short*)take((size_t)SND * SND * 2);
  unsigned short* Wb5  = (unsigned short*)take((size_t)NF * SND * 2);
  float* sum           = (float*)take((size_t)NG * NF * 4);
  float* sumsq         = (float*)take((size_t)NG * NF * 4);  // contiguous after sum
  float* sc            = (float*)take((size_t)NG * NF * 4);
  float* sh            = (float*)take((size_t)NG * NF * 4);
  unsigned short* x1   = (unsigned short*)take((size_t)M * SND * 2);
  unsigned short* hb   = (unsigned short*)take((size_t)M * SND * 2);  // h, reused as x3
  unsigned short* x2   = (unsigned short*)take((size_t)M * SND * 2);

  offsets_kernel<<<2, 256, 0, stream>>>(batch, offs, M);
  wconv_kernel<<<512, 256, 0, stream>>>(W1, W2, W3, W4, W5, Wb1, Wb2, Wb3, Wb4, Wb5);

  const dim3 sgrid(NG, 8);
  const size_t statsBytes = (size_t)NG * NF * 4 * 2;  // sum + sumsq

  // ---- layer 1: x1 = lin1(gn1(x, batch)) ----
  hipMemsetAsync(sum, 0, statsBytes, stream);
  stats_seg<float, NF><<<sgrid, 256, 0, stream>>>(x, offs, sum, sumsq);
  finalize_kernel<<<(NG * NF) / 256, 256, 0, stream>>>(sum, sumsq, gw1, gb1, gm1, offs, M, NF, sc, sh);
  gemm_norm<NF, false, false, false, true><<<dim3(SND / 128, MT), 256, 0, stream>>>(
      x, Wb1, b1, sc, sh, batch, nullptr, nullptr, x1, M, SND);

  // ---- layer 2: h = lin2(prelu(gn2(x1, batch), a2)) ----
  hipMemsetAsync(sum, 0, statsBytes, stream);
  stats_seg<unsigned short, SND><<<sgrid, 256, 0, stream>>>(x1, offs, sum, sumsq);
  finalize_kernel<<<(NG * SND) / 256, 256, 0, stream>>>(sum, sumsq, gw2, gb2, gm2, offs, M, SND, sc, sh);
  gemm_norm<SND, true, true, false, true><<<dim3(SND / 128, MT), 256, 0, stream>>>(
      x1, Wb2, b2, sc, sh, batch, a2, nullptr, hb, M, SND);

  // ---- layer 3: x2 = (lin3(prelu(gn3_global(h), a3)) + x1) / 2 ----
  hipMemsetAsync(sum, 0, statsBytes, stream);
  stats_global<unsigned short><<<512, 256, 0, stream>>>(hb, M, sum, sumsq);
  finalize_kernel<<<1, 256, 0, stream>>>(sum, sumsq, gw3, gb3, gm3, nullptr, M, SND, sc, sh);
  gemm_norm<SND, true, true, true, true><<<dim3(SND / 128, MT), 256, 0, stream>>>(
      hb, Wb3, b3, sc, sh, nullptr, a3, x1, x2, M, SND);

  // ---- layer 4: x3 = (lin4(prelu(gn4(x2, batch), a4)) + x2) / 2 ----
  hipMemsetAsync(sum, 0, statsBytes, stream);
  stats_seg<unsigned short, SND><<<sgrid, 256, 0, stream>>>(x2, offs, sum, sumsq);
  finalize_kernel<<<(NG * SND) / 256, 256, 0, stream>>>(sum, sumsq, gw4, gb4, gm4, offs, M, SND, sc, sh);
  gemm_norm<SND, true, true, true, true><<<dim3(SND / 128, MT), 256, 0, stream>>>(
      x2, Wb4, b4, sc, sh, batch, a4, x2, hb, M, SND);

  // ---- layer 5: out = lin5(prelu(gn5(x3, batch), a5)), fp32 out ----
  hipMemsetAsync(sum, 0, statsBytes, stream);
  stats_seg<unsigned short, SND><<<sgrid, 256, 0, stream>>>(hb, offs, sum, sumsq);
  finalize_kernel<<<(NG * SND) / 256, 256, 0, stream>>>(sum, sumsq, gw5, gb5, gm5, offs, M, SND, sc, sh);
  gemm_norm<SND, true, true, false, false><<<dim3(NF / 128, MT), 256, 0, stream>>>(
      hb, Wb5, b5, sc, sh, batch, a5, nullptr, out, M, NF);
}

// Round 2
// 960.810 us; speedup vs baseline: 1.2420x; 1.2420x over previous
//
#include <hip/hip_runtime.h>
#include <cstddef>
#include <cstdint>

#define NF 512
#define SND 256
#define NG 256
#define EPSV 1e-5f

typedef __attribute__((ext_vector_type(8))) short bf16x8;
typedef __attribute__((ext_vector_type(4))) float f32x4;

__device__ __forceinline__ float bf2f(unsigned short u) {
  return __uint_as_float(((unsigned int)u) << 16);
}
__device__ __forceinline__ unsigned short f2bf(float f) {
  unsigned int u = __float_as_uint(f);
  return (unsigned short)((u + 0x7fffu + ((u >> 16) & 1u)) >> 16);
}
__device__ __forceinline__ unsigned int pack2bf(float a, float b) {
  return (unsigned int)f2bf(a) | ((unsigned int)f2bf(b) << 16);
}

__device__ __forceinline__ void async16(const unsigned short* g, unsigned short* l) {
  __builtin_amdgcn_global_load_lds(
      (const __attribute__((address_space(1))) unsigned int*)g,
      (__attribute__((address_space(3))) unsigned int*)l, 16, 0, 0);
}

// ---------------- small kernels ----------------
__global__ void offsets_kernel(const int* __restrict__ batch, int* __restrict__ offs, int M) {
  int t = threadIdx.x + blockIdx.x * blockDim.x;
  if (t > NG) return;
  if (t == NG) { offs[NG] = M; return; }
  int lo = 0, hi = M;
  while (lo < hi) { int mid = (lo + hi) >> 1; if (batch[mid] < t) lo = mid + 1; else hi = mid; }
  offs[t] = lo;
}

__global__ void wconv_kernel(const float* __restrict__ w1, const float* __restrict__ w2,
                             const float* __restrict__ w3, const float* __restrict__ w4,
                             const float* __restrict__ w5,
                             unsigned short* __restrict__ o1, unsigned short* __restrict__ o2,
                             unsigned short* __restrict__ o3, unsigned short* __restrict__ o4,
                             unsigned short* __restrict__ o5) {
  int i = threadIdx.x + blockIdx.x * 256;
  if (i < 131072) { o1[i] = f2bf(w1[i]); o5[i] = f2bf(w5[i]); }
  if (i < 65536)  { o2[i] = f2bf(w2[i]); o3[i] = f2bf(w3[i]); o4[i] = f2bf(w4[i]); }
}

// ---------------- stats: vectorized loads, LDS block-reduce, then atomics ----------------
// T=float: VE=4 (float4). T=ushort: VE=8 (uint4 of bf16). Optional bf16 write-back (layer 1).
template <typename T, int F, int VE, bool WB, bool GLOB>
__global__ void stats_k(const T* __restrict__ X, const int* __restrict__ offs, int M,
                        float* __restrict__ sum, float* __restrict__ sumsq,
                        unsigned short* __restrict__ xbf) {
  constexpr int TPR = F / VE, RPB = 256 / TPR;
  const int g = GLOB ? 0 : blockIdx.x;
  const int s = GLOB ? 0 : offs[g];
  const int e = GLOB ? M : offs[g + 1];
  const int slot = threadIdx.x / TPR;
  const int f0 = (threadIdx.x % TPR) * VE;
  float a0[VE], a1[VE];
#pragma unroll
  for (int i = 0; i < VE; ++i) { a0[i] = 0.f; a1[i] = 0.f; }

  for (int r = s + (int)blockIdx.y * RPB + slot; r < e; r += (int)gridDim.y * RPB) {
    float v[VE];
    if constexpr (sizeof(T) == 2) {
      const uint4 u = *(const uint4*)((const unsigned short*)X + (size_t)r * F + f0);
      v[0] = __uint_as_float(u.x << 16); v[1] = __uint_as_float(u.x & 0xffff0000u);
      v[2] = __uint_as_float(u.y << 16); v[3] = __uint_as_float(u.y & 0xffff0000u);
      v[4] = __uint_as_float(u.z << 16); v[5] = __uint_as_float(u.z & 0xffff0000u);
      v[6] = __uint_as_float(u.w << 16); v[7] = __uint_as_float(u.w & 0xffff0000u);
    } else {
      const float4 u = *(const float4*)((const float*)X + (size_t)r * F + f0);
      v[0] = u.x; v[1] = u.y; v[2] = u.z; v[3] = u.w;
    }
#pragma unroll
    for (int i = 0; i < VE; ++i) { a0[i] += v[i]; a1[i] += v[i] * v[i]; }
    if constexpr (WB) {  // bf16 copy (layer 1: fp32 -> bf16 into A buffer), VE==4
      *(uint2*)(xbf + (size_t)r * F + f0) = make_uint2(pack2bf(v[0], v[1]), pack2bf(v[2], v[3]));
    }
  }

  __shared__ float red[256 * VE];  // [slot][F]
  __syncthreads();
#pragma unroll
  for (int i = 0; i < VE; ++i) red[slot * F + f0 + i] = a0[i];
  __syncthreads();
  if (slot == 0) {
#pragma unroll
    for (int i = 0; i < VE; ++i) {
      float t = 0.f;
      for (int sl = 0; sl < RPB; ++sl) t += red[sl * F + f0 + i];
      atomicAdd(&sum[g * F + f0 + i], t);
    }
  }
  __syncthreads();
#pragma unroll
  for (int i = 0; i < VE; ++i) red[slot * F + f0 + i] = a1[i];
  __syncthreads();
  if (slot == 0) {
#pragma unroll
    for (int i = 0; i < VE; ++i) {
      float t = 0.f;
      for (int sl = 0; sl < RPB; ++sl) t += red[sl * F + f0 + i];
      atomicAdd(&sumsq[g * F + f0 + i], t);
    }
  }
}

__global__ void finalize_kernel(const float* __restrict__ sum, const float* __restrict__ sumsq,
                                const float* __restrict__ w, const float* __restrict__ b,
                                const float* __restrict__ ms, const int* __restrict__ offs,
                                int fixed_cnt, int F,
                                float* __restrict__ sc, float* __restrict__ sh) {
  int idx = threadIdx.x + blockIdx.x * 256;
  int g = idx / F, f = idx - g * F;
  float cnt = offs ? (float)(offs[g + 1] - offs[g]) : (float)fixed_cnt;
  cnt = fmaxf(cnt, 1.0f);
  float mean = sum[idx] / cnt;
  float ex2  = sumsq[idx] / cnt;
  float mm = mean * ms[f];
  float var = ex2 - 2.f * mm * mean + mm * mm;  // E[(x-mean*ms)^2]
  float rstd = rsqrtf(var + EPSV);
  float s = w[f] * rstd;
  sc[idx] = s;
  sh[idx] = b[f] - mm * s;
}

// ---------------- normalize (+prelu): bf16 in -> bf16 out, streaming ----------------
template <int K, bool PRELU, bool GLOB>
__global__ void norm_act(const unsigned short* __restrict__ Xin, unsigned short* __restrict__ Aout,
                         const float* __restrict__ SC, const float* __restrict__ SH,
                         const int* __restrict__ batch, const float* __restrict__ pa, int M) {
  constexpr int TPR = K / 8, RPB = 256 / TPR;
  const int row = blockIdx.x * RPB + threadIdx.x / TPR;
  if (row >= M) return;
  const int f0 = (threadIdx.x % TPR) * 8;
  const int g = GLOB ? 0 : batch[row];
  const float a = PRELU ? pa[0] : 0.f;
  const uint4 u = *(const uint4*)(Xin + (size_t)row * K + f0);
  const float4 s0 = *(const float4*)(SC + (size_t)g * K + f0);
  const float4 s1 = *(const float4*)(SC + (size_t)g * K + f0 + 4);
  const float4 h0 = *(const float4*)(SH + (size_t)g * K + f0);
  const float4 h1 = *(const float4*)(SH + (size_t)g * K + f0 + 4);
  float v[8];
  v[0] = __uint_as_float(u.x << 16); v[1] = __uint_as_float(u.x & 0xffff0000u);
  v[2] = __uint_as_float(u.y << 16); v[3] = __uint_as_float(u.y & 0xffff0000u);
  v[4] = __uint_as_float(u.z << 16); v[5] = __uint_as_float(u.z & 0xffff0000u);
  v[6] = __uint_as_float(u.w << 16); v[7] = __uint_as_float(u.w & 0xffff0000u);
  v[0] = fmaf(v[0], s0.x, h0.x); v[1] = fmaf(v[1], s0.y, h0.y);
  v[2] = fmaf(v[2], s0.z, h0.z); v[3] = fmaf(v[3], s0.w, h0.w);
  v[4] = fmaf(v[4], s1.x, h1.x); v[5] = fmaf(v[5], s1.y, h1.y);
  v[6] = fmaf(v[6], s1.z, h1.z); v[7] = fmaf(v[7], s1.w, h1.w);
  if (PRELU) {
#pragma unroll
    for (int i = 0; i < 8; ++i) v[i] = v[i] >= 0.f ? v[i] : a * v[i];
  }
  *(uint4*)(Aout + (size_t)row * K + f0) =
      make_uint4(pack2bf(v[0], v[1]), pack2bf(v[2], v[3]),
                 pack2bf(v[4], v[5]), pack2bf(v[6], v[7]));
}

// ---------------- clean bf16 MFMA GEMM, global_load_lds + XOR swizzle ----------------
// out[m][n] = sum_k A[m][k]*B[n][k] + lb[n]  (opt: +resid, *0.5; fp32 or bf16 out)
// A is padded to M rounded up to 128 rows (pad rows hold junk, masked in epilogue).
template <int K, bool RESID, bool OUT_BF>
__global__ __launch_bounds__(256, 4)
void gemm_bf16(const unsigned short* __restrict__ A, const unsigned short* __restrict__ Bw,
               const float* __restrict__ lb_, const unsigned short* __restrict__ resid,
               void* __restrict__ outv, int M, int N) {
  __shared__ __align__(16) unsigned short sA[128 * 64];
  __shared__ __align__(16) unsigned short sB[128 * 64];
  const int tid = threadIdx.x;
  const int wave = tid >> 6, lane = tid & 63;
  const int m0 = blockIdx.y * 128, n0 = blockIdx.x * 128;
  const int wm = wave & 1, wn = wave >> 1;
  const int qd = lane >> 4, l15 = lane & 15;

  // staging: issue i covers rows wave*32+i*8 .. +7; lane -> (srow, phys chunk schunk)
  const int srow = lane >> 3;        // 0..7
  const int schunk = lane & 7;       // physical LDS chunk this lane fills
  const int gchunk = schunk ^ srow;  // logical/global source chunk (swizzle)

  f32x4 acc[4][4];
#pragma unroll
  for (int mi = 0; mi < 4; ++mi)
#pragma unroll
    for (int ni = 0; ni < 4; ++ni) acc[mi][ni] = (f32x4){0.f, 0.f, 0.f, 0.f};

  const unsigned short* Abase = A + (size_t)m0 * K;
  const unsigned short* Bbase = Bw + (size_t)n0 * K;

  for (int kt = 0; kt < K / 64; ++kt) {
    const int kOff = kt * 64 + gchunk * 8;
#pragma unroll
    for (int i = 0; i < 4; ++i) {
      const int r = wave * 32 + i * 8 + srow;
      async16(Abase + (size_t)r * K + kOff, &sA[(wave * 4 + i) * 512]);
      async16(Bbase + (size_t)r * K + kOff, &sB[(wave * 4 + i) * 512]);
    }
    __syncthreads();  // compiler emits vmcnt(0) drain before barrier
#pragma unroll
    for (int ks = 0; ks < 2; ++ks) {
      bf16x8 af[4], bfr[4];
      const int pc = ((ks * 4 + qd) ^ (l15 & 7)) * 8;
#pragma unroll
      for (int mi = 0; mi < 4; ++mi)
        af[mi] = *(const bf16x8*)&sA[(wm * 64 + mi * 16 + l15) * 64 + pc];
#pragma unroll
      for (int ni = 0; ni < 4; ++ni)
        bfr[ni] = *(const bf16x8*)&sB[(wn * 64 + ni * 16 + l15) * 64 + pc];
#pragma unroll
      for (int mi = 0; mi < 4; ++mi)
#pragma unroll
        for (int ni = 0; ni < 4; ++ni)
          acc[mi][ni] = __builtin_amdgcn_mfma_f32_16x16x32_bf16(af[mi], bfr[ni], acc[mi][ni], 0, 0, 0);
    }
    __syncthreads();
  }

  // epilogue: C/D row = qd*4+i (m), col = l15 (n)
  float lb[4];
#pragma unroll
  for (int ni = 0; ni < 4; ++ni) lb[ni] = lb_[n0 + wn * 64 + ni * 16 + l15];
  float* outF = (float*)outv;
  unsigned short* outH = (unsigned short*)outv;
#pragma unroll
  for (int mi = 0; mi < 4; ++mi) {
#pragma unroll
    for (int i = 0; i < 4; ++i) {
      const int row = m0 + wm * 64 + mi * 16 + qd * 4 + i;
      if (row >= M) continue;
#pragma unroll
      for (int ni = 0; ni < 4; ++ni) {
        const int col = n0 + wn * 64 + ni * 16 + l15;
        float v = acc[mi][ni][i] + lb[ni];
        if (RESID) v = 0.5f * (v + bf2f(resid[(size_t)row * N + col]));
        if (OUT_BF) outH[(size_t)row * N + col] = f2bf(v);
        else        outF[(size_t)row * N + col] = v;
      }
    }
  }
}

// ---------------- launch ----------------
extern "C" void kernel_launch(void* const* d_in, const int* in_sizes, int n_in,
                              void* d_out, int out_size, void* d_ws, size_t ws_size,
                              hipStream_t stream) {
  const float* x    = (const float*)d_in[0];
  const int* batch  = (const int*)d_in[1];
  const float* gw1 = (const float*)d_in[2],  *gb1 = (const float*)d_in[3],  *gm1 = (const float*)d_in[4];
  const float* gw2 = (const float*)d_in[5],  *gb2 = (const float*)d_in[6],  *gm2 = (const float*)d_in[7];
  const float* gw3 = (const float*)d_in[8],  *gb3 = (const float*)d_in[9],  *gm3 = (const float*)d_in[10];
  const float* gw4 = (const float*)d_in[11], *gb4 = (const float*)d_in[12], *gm4 = (const float*)d_in[13];
  const float* gw5 = (const float*)d_in[14], *gb5 = (const float*)d_in[15], *gm5 = (const float*)d_in[16];
  const float* W1 = (const float*)d_in[17], *b1 = (const float*)d_in[18];
  const float* W2 = (const float*)d_in[19], *b2 = (const float*)d_in[20];
  const float* W3 = (const float*)d_in[21], *b3 = (const float*)d_in[22];
  const float* W4 = (const float*)d_in[23], *b4 = (const float*)d_in[24];
  const float* W5 = (const float*)d_in[25], *b5 = (const float*)d_in[26];
  const float* a2 = (const float*)d_in[27], *a3 = (const float*)d_in[28];
  const float* a4 = (const float*)d_in[29], *a5 = (const float*)d_in[30];
  float* out = (float*)d_out;
  (void)n_in; (void)out_size; (void)ws_size;

  const int M = in_sizes[0] / NF;
  const int MT = (M + 127) / 128;
  const int M_pad = MT * 128;

  char* wsp = (char*)d_ws;
  size_t off = 0;
  auto take = [&](size_t bytes) -> void* {
    void* p = wsp + off;
    off = (off + bytes + 255) & ~(size_t)255;
    return p;
  };
  int* offs            = (int*)take((NG + 1) * sizeof(int));
  unsigned short* Wb1  = (unsigned short*)take((size_t)SND * NF * 2);
  unsigned short* Wb2  = (unsigned short*)take((size_t)SND * SND * 2);
  unsigned short* Wb3  = (unsigned short*)take((size_t)SND * SND * 2);
  unsigned short* Wb4  = (unsigned short*)take((size_t)SND * SND * 2);
  unsigned short* Wb5  = (unsigned short*)take((size_t)NF * SND * 2);
  float* sum           = (float*)take((size_t)NG * NF * 4);
  float* sumsq         = (float*)take((size_t)NG * NF * 4);  // contiguous after sum
  float* sc            = (float*)take((size_t)NG * NF * 4);
  float* sh            = (float*)take((size_t)NG * NF * 4);
  unsigned short* B1   = (unsigned short*)take((size_t)M_pad * SND * 2);
  unsigned short* B2   = (unsigned short*)take((size_t)M_pad * SND * 2);
  unsigned short* Abuf = (unsigned short*)take((size_t)M_pad * NF * 2);

  offsets_kernel<<<2, 256, 0, stream>>>(batch, offs, M);
  wconv_kernel<<<512, 256, 0, stream>>>(W1, W2, W3, W4, W5, Wb1, Wb2, Wb3, Wb4, Wb5);

  const size_t statsBytes = (size_t)NG * NF * 4 * 2;  // sum + sumsq

  // ---- layer 1: x1 = lin1(gn1(x, batch))  [stats also emits bf16(x) into Abuf] ----
  hipMemsetAsync(sum, 0, statsBytes, stream);
  stats_k<float, NF, 4, true, false><<<dim3(NG, 8), 256, 0, stream>>>(x, offs, M, sum, sumsq, Abuf);
  finalize_kernel<<<(NG * NF) / 256, 256, 0, stream>>>(sum, sumsq, gw1, gb1, gm1, offs, M, NF, sc, sh);
  norm_act<NF, false, false><<<(M + 3) / 4, 256, 0, stream>>>(Abuf, Abuf, sc, sh, batch, nullptr, M);
  gemm_bf16<NF, false, true><<<dim3(SND / 128, MT), 256, 0, stream>>>(Abuf, Wb1, b1, nullptr, B1, M, SND);

  // ---- layer 2: h = lin2(prelu(gn2(x1, batch), a2)) ----
  hipMemsetAsync(sum, 0, statsBytes, stream);
  stats_k<unsigned short, SND, 8, false, false><<<dim3(NG, 4), 256, 0, stream>>>(B1, offs, M, sum, sumsq, nullptr);
  finalize_kernel<<<(NG * SND) / 256, 256, 0, stream>>>(sum, sumsq, gw2, gb2, gm2, offs, M, SND, sc, sh);
  norm_act<SND, true, false><<<(M + 7) / 8, 256, 0, stream>>>(B1, Abuf, sc, sh, batch, a2, M);
  gemm_bf16<SND, false, true><<<dim3(SND / 128, MT), 256, 0, stream>>>(Abuf, Wb2, b2, nullptr, B2, M, SND);

  // ---- layer 3: x2 = (lin3(prelu(gn3_global(h), a3)) + x1) / 2 ----
  hipMemsetAsync(sum, 0, statsBytes, stream);
  stats_k<unsigned short, SND, 8, false, true><<<dim3(1, 512), 256, 0, stream>>>(B2, offs, M, sum, sumsq, nullptr);
  finalize_kernel<<<1, 256, 0, stream>>>(sum, sumsq, gw3, gb3, gm3, nullptr, M, SND, sc, sh);
  norm_act<SND, true, true><<<(M + 7) / 8, 256, 0, stream>>>(B2, Abuf, sc, sh, nullptr, a3, M);
  gemm_bf16<SND, true, true><<<dim3(SND / 128, MT), 256, 0, stream>>>(Abuf, Wb3, b3, B1, B2, M, SND);

  // ---- layer 4: x3 = (lin4(prelu(gn4(x2, batch), a4)) + x2) / 2 ----
  hipMemsetAsync(sum, 0, statsBytes, stream);
  stats_k<unsigned short, SND, 8, false, false><<<dim3(NG, 4), 256, 0, stream>>>(B2, offs, M, sum, sumsq, nullptr);
  finalize_kernel<<<(NG * SND) / 256, 256, 0, stream>>>(sum, sumsq, gw4, gb4, gm4, offs, M, SND, sc, sh);
  norm_act<SND, true, false><<<(M + 7) / 8, 256, 0, stream>>>(B2, Abuf, sc, sh, batch, a4, M);
  gemm_bf16<SND, true, true><<<dim3(SND / 128, MT), 256, 0, stream>>>(Abuf, Wb4, b4, B2, B1, M, SND);

  // ---- layer 5: out = lin5(prelu(gn5(x3, batch), a5)), fp32 out ----
  hipMemsetAsync(sum, 0, statsBytes, stream);
  stats_k<unsigned short, SND, 8, false, false><<<dim3(NG, 4), 256, 0, stream>>>(B1, offs, M, sum, sumsq, nullptr);
  finalize_kernel<<<(NG * SND) / 256, 256, 0, stream>>>(sum, sumsq, gw5, gb5, gm5, offs, M, SND, sc, sh);
  norm_act<SND, true, false><<<(M + 7) / 8, 256, 0, stream>>>(B1, Abuf, sc, sh, batch, a5, M);
  gemm_bf16<SND, false, false><<<dim3(NF / 128, MT), 256, 0, stream>>>(Abuf, Wb5, b5, nullptr, out, M, NF);
}